// Round 1
// 76.089 us; speedup vs baseline: 1.0243x; 1.0243x over previous
//
#include <hip/hip_runtime.h>

// Fully fused: table build (per block, in LDS) + batch circuit + linear head
// + softmax in ONE launch.  The 4x81 difference tensor is batch-uniform;
// rebuilding it per block costs ~1us (parallel across CUs) and removes the
// second kernel launch + inter-kernel serialization.
//
// Main loop: 4 rows/thread as two float2-packed row PAIRS -> every table
// coefficient is a scalar broadcast shared by both halves (pk-fma friendly),
// and each LDS tile read is amortized over 4 rows.  Tiles padded 9->12 floats
// so each is 2x ds_read_b128 + 1x ds_read_b32, 16B-aligned, broadcast
// (conflict-free).  x loads are issued BEFORE the table build so HBM latency
// hides behind it.  lin_b is folded into table entry [0][0][0].

__device__ __forceinline__ float layer_angle(const float* __restrict__ w,
                                             int l, int idx) {
    float ang = 0.f;
    #pragma unroll
    for (int g = 0; g < 4; ++g) {
        int cb = (idx >> (3 - g)) & 1;                 // control = wire g
        int tb = (idx >> (3 - ((g + 1) & 3))) & 1;     // target  = wire (g+1)%4
        if (cb) ang += (tb ? 0.5f : -0.5f) * w[l * 4 + g];
    }
    return ang;
}

__device__ __forceinline__ float2 f2fmas(float2 a, float b, float2 c) {
    return make_float2(fmaf(a.x, b, c.x), fmaf(a.y, b, c.y));
}
__device__ __forceinline__ float2 f2fma(float2 a, float2 b, float2 c) {
    return make_float2(fmaf(a.x, b.x, c.x), fmaf(a.y, b.y, c.y));
}
__device__ __forceinline__ float2 f2add(float2 a, float2 b) {
    return make_float2(a.x + b.x, a.y + b.y);
}

__device__ __forceinline__ void compute_chunk(
    const float4 (&xv)[4][4],
    const float (&tabs)[4][9][12],
    float* __restrict__ out,
    int base, int nrows, int t)
{
    float2 d[2] = {make_float2(0.f, 0.f), make_float2(0.f, 0.f)};

    #pragma unroll
    for (int s = 0; s < 4; ++s) {
        // trig basis for the 4 rows, packed as pairs (rows 0,1) and (2,3)
        float2 C0[2], S0[2], C1v[2], S1[2], C2[2], S2[2], C3[2], S3[2];
        #pragma unroll
        for (int r = 0; r < 4; ++r) {
            const int lo = (s >> 1) * 2;
            float4 va = xv[r][lo], vb = xv[r][lo + 1];
            float a0, a1, a2, a3;
            if (s & 1) { a0 = va.z; a1 = va.w; a2 = vb.z; a3 = vb.w; }
            else       { a0 = va.x; a1 = va.y; a2 = vb.x; a3 = vb.y; }
            const int p = r >> 1;
            float c, sn;
            __sincosf(a0, &sn, &c);
            if (r & 1) { C0[p].y = c;  S0[p].y = sn; } else { C0[p].x = c;  S0[p].x = sn; }
            __sincosf(a1, &sn, &c);
            if (r & 1) { C1v[p].y = c; S1[p].y = sn; } else { C1v[p].x = c; S1[p].x = sn; }
            __sincosf(a2, &sn, &c);
            if (r & 1) { C2[p].y = c;  S2[p].y = sn; } else { C2[p].x = c;  S2[p].x = sn; }
            __sincosf(a3, &sn, &c);
            if (r & 1) { C3[p].y = c;  S3[p].y = sn; } else { C3[p].x = c;  S3[p].x = sn; }
        }

        #pragma unroll
        for (int t0 = 0; t0 < 3; ++t0) {
            float2 acc[2] = {make_float2(0.f, 0.f), make_float2(0.f, 0.f)};
            #pragma unroll
            for (int t1 = 0; t1 < 3; ++t1) {
                const float* tp = &tabs[s][t0 * 3 + t1][0];
                float4 q0 = *(const float4*)tp;        // k0..k3
                float4 q1 = *(const float4*)(tp + 4);  // k4..k7
                float  k8 = tp[8];
                #pragma unroll
                for (int p = 0; p < 2; ++p) {
                    float2 u0 = f2fmas(S3[p], q0.z,
                                 f2fmas(C3[p], q0.y, make_float2(q0.x, q0.x)));
                    float2 u1 = f2fmas(S3[p], q1.y,
                                 f2fmas(C3[p], q1.x, make_float2(q0.w, q0.w)));
                    float2 u2 = f2fmas(S3[p], k8,
                                 f2fmas(C3[p], q1.w, make_float2(q1.z, q1.z)));
                    float2 a1v = f2fma(S2[p], u2, f2fma(C2[p], u1, u0));
                    if      (t1 == 0) acc[p] = f2add(acc[p], a1v);
                    else if (t1 == 1) acc[p] = f2fma(C1v[p], a1v, acc[p]);
                    else              acc[p] = f2fma(S1[p],  a1v, acc[p]);
                }
            }
            #pragma unroll
            for (int p = 0; p < 2; ++p) {
                if      (t0 == 0) d[p] = f2add(d[p], acc[p]);
                else if (t0 == 1) d[p] = f2fma(C0[p], acc[p], d[p]);
                else              d[p] = f2fma(S0[p], acc[p], d[p]);
            }
        }
    }

    #pragma unroll
    for (int r = 0; r < 4; ++r) {
        int row = base + r * 256 + t;
        if (row < nrows) {
            float dv = (r & 1) ? d[r >> 1].y : d[r >> 1].x;
            float p0 = 1.f / (1.f + __expf(-dv));
            *(float2*)(out + (size_t)row * 2) = make_float2(p0, 1.f - p0);
        }
    }
}

__global__ __launch_bounds__(256) void fused_qcircuit(
    const float* __restrict__ x,
    const float* __restrict__ weights,
    const float* __restrict__ lin_w,
    const float* __restrict__ lin_b,
    float* __restrict__ out,
    int nrows)
{
    __shared__ float2 U1[256], U2[256], U[256];   // row-major [i*16+j]
    __shared__ float zeta[4][16];
    __shared__ float G[4][256];
    __shared__ float A[4][3][64];
    __shared__ float B[4][9][16];
    __shared__ float C1[4][27][4];
    __shared__ __align__(16) float tabs[4][9][12];  // [s][t0*3+t1][t2*3+t3] pad 12

    int t = threadIdx.x;
    int i = t >> 4, j = t & 15;

    // ---- issue this block's x loads first: in flight during table build ----
    int base = blockIdx.x * 1024;
    float4 xv[4][4];
    #pragma unroll
    for (int r = 0; r < 4; ++r) {
        int row = base + r * 256 + t;
        int rc = row < nrows ? row : 0;
        const float4* xp = (const float4*)(x + (size_t)rc * 16);
        xv[r][0] = xp[0]; xv[r][1] = xp[1]; xv[r][2] = xp[2]; xv[r][3] = xp[3];
    }
    float bias = lin_b[0] - lin_b[1];

    // ---- table build (identical math to the old precompute kernel) ----
    // U1 = Hhat * D0   (Hhat[i][j] = (-1)^popc(i&j), unnormalized)
    {
        float sgn = (__popc(i & j) & 1) ? -1.f : 1.f;
        float a = layer_angle(weights, 0, j);
        U1[t] = make_float2(sgn * __cosf(a), sgn * __sinf(a));
    }
    // zeta[s][k] = sum_w (lin_w[0,4s+w]-lin_w[1,4s+w]) * (-1)^{bit(3-w) of k}
    if (t < 64) {
        int s = t >> 4, k = t & 15;
        float z = 0.f;
        #pragma unroll
        for (int w = 0; w < 4; ++w) {
            float sg = ((k >> (3 - w)) & 1) ? -1.f : 1.f;
            z += (lin_w[s * 4 + w] - lin_w[16 + s * 4 + w]) * sg;
        }
        zeta[s][k] = z;
    }
    __syncthreads();
    // U2 = Hhat * D1 * U1
    {
        float ar = 0.f, ai = 0.f;
        for (int k = 0; k < 16; ++k) {
            float sgn = (__popc(i & k) & 1) ? -1.f : 1.f;
            float a = layer_angle(weights, 1, k);
            float cr = sgn * __cosf(a), ci = sgn * __sinf(a);
            float2 u = U1[k * 16 + j];
            ar += cr * u.x - ci * u.y;
            ai += cr * u.y + ci * u.x;
        }
        U2[t] = make_float2(ar, ai);
    }
    __syncthreads();
    // U = Hhat * D2 * U2
    {
        float ar = 0.f, ai = 0.f;
        for (int k = 0; k < 16; ++k) {
            float sgn = (__popc(i & k) & 1) ? -1.f : 1.f;
            float a = layer_angle(weights, 2, k);
            float cr = sgn * __cosf(a), ci = sgn * __sinf(a);
            float2 u = U2[k * 16 + j];
            ar += cr * u.x - ci * u.y;
            ai += cr * u.y + ci * u.x;
        }
        U[t] = make_float2(ar, ai);
    }
    __syncthreads();
    // G[s][i*16+j] = sum_k zeta[s][k] * Re(conj(U[k,i]) U[k,j])
    {
        float g[4] = {0, 0, 0, 0};
        for (int k = 0; k < 16; ++k) {
            float2 uki = U[k * 16 + i], ukj = U[k * 16 + j];
            float p = uki.x * ukj.x + uki.y * ukj.y;
            #pragma unroll
            for (int s = 0; s < 4; ++s) g[s] += zeta[s][k] * p;
        }
        #pragma unroll
        for (int s = 0; s < 4; ++s) G[s][t] = g[s];
    }
    __syncthreads();
    // Fold wire3 (LSB): A[s][t3][ih*8+jh]
    for (int e = t; e < 768; e += 256) {
        int m = e / 192, r = e % 192;
        int t3 = r / 64, q = r % 64;
        int ih = q >> 3, jh = q & 7;
        float g00 = G[m][(ih * 2 + 0) * 16 + jh * 2 + 0];
        float g01 = G[m][(ih * 2 + 0) * 16 + jh * 2 + 1];
        float g10 = G[m][(ih * 2 + 1) * 16 + jh * 2 + 0];
        float g11 = G[m][(ih * 2 + 1) * 16 + jh * 2 + 1];
        A[m][t3][q] = (t3 == 0) ? g00 + g11 : (t3 == 1) ? g00 - g11 : g01 + g10;
    }
    __syncthreads();
    // Fold wire2: B[s][t2*3+t3][ih*4+jh]
    for (int e = t; e < 576; e += 256) {
        int m = e / 144, r = e % 144;
        int t2 = r / 48; r %= 48;
        int t3 = r / 16, q = r % 16;
        int ih = q >> 2, jh = q & 3;
        float a00 = A[m][t3][(ih * 2 + 0) * 8 + jh * 2 + 0];
        float a01 = A[m][t3][(ih * 2 + 0) * 8 + jh * 2 + 1];
        float a10 = A[m][t3][(ih * 2 + 1) * 8 + jh * 2 + 0];
        float a11 = A[m][t3][(ih * 2 + 1) * 8 + jh * 2 + 1];
        B[m][t2 * 3 + t3][q] = (t2 == 0) ? a00 + a11
                             : (t2 == 1) ? a00 - a11 : a01 + a10;
    }
    __syncthreads();
    // Fold wire1: C1[s][t1*9+t2*3+t3][ih*2+jh]
    for (int e = t; e < 432; e += 256) {
        int m = e / 108, r = e % 108;
        int t1 = r / 36; r %= 36;
        int t23 = r / 4, q = r % 4;
        int ih = q >> 1, jh = q & 1;
        float b00 = B[m][t23][(ih * 2 + 0) * 4 + jh * 2 + 0];
        float b01 = B[m][t23][(ih * 2 + 0) * 4 + jh * 2 + 1];
        float b10 = B[m][t23][(ih * 2 + 1) * 4 + jh * 2 + 0];
        float b11 = B[m][t23][(ih * 2 + 1) * 4 + jh * 2 + 1];
        C1[m][t1 * 9 + t23][q] = (t1 == 0) ? b00 + b11
                               : (t1 == 1) ? b00 - b11 : b01 + b10;
    }
    __syncthreads();
    // Fold wire0 + write to padded tile layout.  Scale: (1/64)^2 H-norm,
    // (1/2)^4 half-angle basis.  lin_b difference folded into [0][0][0].
    {
        const float scale = 1.f / 65536.f;
        for (int e = t; e < 324; e += 256) {
            int m = e / 81, r = e % 81;
            int t0 = r / 27, t123 = r % 27;
            const float* c = C1[m][t123];
            float v = (t0 == 0) ? c[0] + c[3] : (t0 == 1) ? c[0] - c[3]
                                              : c[1] + c[2];
            float val = v * scale;
            if (e == 0) val += bias;
            int t1 = t123 / 9, k = t123 % 9;
            tabs[m][t0 * 3 + t1][k] = val;
        }
    }
    __syncthreads();

    // ---- batch compute ----
    compute_chunk(xv, tabs, out, base, nrows, t);

    // grid-stride fallback (dead when grid covers nrows exactly)
    for (base += gridDim.x * 1024; base < nrows; base += gridDim.x * 1024) {
        #pragma unroll
        for (int r = 0; r < 4; ++r) {
            int row = base + r * 256 + t;
            int rc = row < nrows ? row : 0;
            const float4* xp = (const float4*)(x + (size_t)rc * 16);
            xv[r][0] = xp[0]; xv[r][1] = xp[1]; xv[r][2] = xp[2]; xv[r][3] = xp[3];
        }
        compute_chunk(xv, tabs, out, base, nrows, t);
    }
}

extern "C" void kernel_launch(void* const* d_in, const int* in_sizes, int n_in,
                              void* d_out, int out_size, void* d_ws, size_t ws_size,
                              hipStream_t stream) {
    const float* x       = (const float*)d_in[0];
    const float* weights = (const float*)d_in[1];
    const float* lin_w   = (const float*)d_in[2];
    const float* lin_b   = (const float*)d_in[3];
    float* out = (float*)d_out;

    int nrows = in_sizes[0] / 16;
    int grid = (nrows + 1023) / 1024;
    if (grid < 1) grid = 1;
    fused_qcircuit<<<grid, 256, 0, stream>>>(x, weights, lin_w, lin_b, out, nrows);
}